// Round 1
// baseline (361.958 us; speedup 1.0000x reference)
//
#include <hip/hip_runtime.h>
#include <math.h>

#define BATCH 256
#define CH 512
#define SE_CH 32
#define HW 1024  // 32*32

// ---------------- Kernel 1: per-(b,c) plane mean ----------------
// One wave (64 lanes) per 1024-float contiguous plane: 4 float4 loads/lane.
__global__ void se_mean_kernel(const float* __restrict__ x,
                               float* __restrict__ mean,
                               int nplanes) {
    const int lane = threadIdx.x & 63;
    const int wave_in_block = threadIdx.x >> 6;
    const int waves_per_block = blockDim.x >> 6;
    int wid = blockIdx.x * waves_per_block + wave_in_block;
    const int nwaves = gridDim.x * waves_per_block;

    for (int p = wid; p < nplanes; p += nwaves) {
        const float4* px = (const float4*)(x + (size_t)p * HW);
        float s = 0.0f;
#pragma unroll
        for (int j = 0; j < 4; ++j) {
            float4 v = px[lane + j * 64];
            s += (v.x + v.y) + (v.z + v.w);
        }
        // 64-lane butterfly reduce
#pragma unroll
        for (int off = 32; off > 0; off >>= 1)
            s += __shfl_down(s, off, 64);
        if (lane == 0)
            mean[p] = s * (1.0f / (float)HW);
    }
}

// ---------------- Kernel 2: FC1 -> relu -> FC2 -> sigmoid/bias ----------------
// One block (256 threads) per batch element. Tiny.
__global__ void se_fc_kernel(const float* __restrict__ mean,
                             const float* __restrict__ fc1_w,  // [SE_CH][CH]
                             const float* __restrict__ fc1_b,  // [SE_CH]
                             const float* __restrict__ fc2_w,  // [2*CH][SE_CH]
                             const float* __restrict__ fc2_b,  // [2*CH]
                             float* __restrict__ scale,        // [BATCH][CH]
                             float* __restrict__ bias) {       // [BATCH][CH]
    const int b = blockIdx.x;
    const int t = threadIdx.x;
    __shared__ float m[CH];
    __shared__ float se[SE_CH];

    for (int i = t; i < CH; i += blockDim.x)
        m[i] = mean[b * CH + i];
    __syncthreads();

    if (t < SE_CH) {
        float acc = fc1_b[t];
        const float* wr = fc1_w + t * CH;
#pragma unroll 8
        for (int k = 0; k < CH; ++k)
            acc = fmaf(wr[k], m[k], acc);
        se[t] = fmaxf(acc, 0.0f);
    }
    __syncthreads();

    // 2*CH = 1024 outputs, 256 threads -> 4 per thread
    for (int o = t; o < 2 * CH; o += blockDim.x) {
        float acc = fc2_b[o];
        const float* wr = fc2_w + o * SE_CH;
#pragma unroll
        for (int k = 0; k < SE_CH; ++k)
            acc = fmaf(wr[k], se[k], acc);
        if (o < CH)
            scale[b * CH + o] = 1.0f / (1.0f + expf(-acc));
        else
            bias[b * CH + (o - CH)] = acc;
    }
}

// ---------------- Kernel 3: out = x * scale[plane] + bias[plane] ----------------
__global__ void se_apply_kernel(const float* __restrict__ x,
                                const float* __restrict__ scale,
                                const float* __restrict__ bias,
                                float* __restrict__ out,
                                size_t n4) {
    size_t i = blockIdx.x * (size_t)blockDim.x + threadIdx.x;
    const size_t stride = (size_t)gridDim.x * blockDim.x;
    const float4* x4 = (const float4*)x;
    float4* o4 = (float4*)out;

    for (; i < n4; i += stride) {
        const int plane = (int)(i >> 8);  // 256 float4 per 1024-elem plane
        const float s = scale[plane];
        const float bi = bias[plane];
        float4 v = x4[i];
        float4 r;
        r.x = fmaf(v.x, s, bi);
        r.y = fmaf(v.y, s, bi);
        r.z = fmaf(v.z, s, bi);
        r.w = fmaf(v.w, s, bi);
        o4[i] = r;
    }
}

extern "C" void kernel_launch(void* const* d_in, const int* in_sizes, int n_in,
                              void* d_out, int out_size, void* d_ws, size_t ws_size,
                              hipStream_t stream) {
    const float* x     = (const float*)d_in[0];
    const float* fc1_w = (const float*)d_in[1];
    const float* fc1_b = (const float*)d_in[2];
    const float* fc2_w = (const float*)d_in[3];
    const float* fc2_b = (const float*)d_in[4];
    float* out = (float*)d_out;

    const int nplanes = BATCH * CH;            // 131072
    float* mean  = (float*)d_ws;               // 131072 f32
    float* scale = mean + nplanes;             // 131072 f32
    float* bias  = scale + nplanes;            // 131072 f32

    // Kernel 1: plane means. 2048 blocks * 256 thr = 8192 waves, grid-stride.
    se_mean_kernel<<<2048, 256, 0, stream>>>(x, mean, nplanes);

    // Kernel 2: FC stack, one block per batch element.
    se_fc_kernel<<<BATCH, 256, 0, stream>>>(mean, fc1_w, fc1_b, fc2_w, fc2_b,
                                            scale, bias);

    // Kernel 3: streaming apply.
    const size_t n4 = (size_t)BATCH * CH * HW / 4;  // 33,554,432
    se_apply_kernel<<<2048, 256, 0, stream>>>(x, scale, bias, out, n4);
}

// Round 2
// 303.560 us; speedup vs baseline: 1.1924x; 1.1924x over previous
//
#include <hip/hip_runtime.h>
#include <math.h>

#define BATCH 256
#define CH 512
#define SE_CH 32
#define HW 1024            // 32*32
#define CHUNK_B 64         // batches per chunk -> 64*512*1024*4 = 128 MB of x, fits L3 with out-writes
#define NCHUNK (BATCH / CHUNK_B)
#define CHUNK_PLANES (CHUNK_B * CH)   // 32768 planes * 4KB = 128 MB

typedef float f32x4 __attribute__((ext_vector_type(4)));

// ---------------- Kernel 1: per-(b,c) plane mean ----------------
// One wave (64 lanes) per 1024-float contiguous plane: 4 x 16B loads/lane.
// Plain loads on purpose: they populate L3 for the apply pass.
__global__ void se_mean_kernel(const float* __restrict__ x,
                               float* __restrict__ mean,
                               int nplanes) {
    const int lane = threadIdx.x & 63;
    const int wave_in_block = threadIdx.x >> 6;
    const int waves_per_block = blockDim.x >> 6;
    int wid = blockIdx.x * waves_per_block + wave_in_block;
    const int nwaves = gridDim.x * waves_per_block;

    for (int p = wid; p < nplanes; p += nwaves) {
        const f32x4* px = (const f32x4*)(x + (size_t)p * HW);
        float s = 0.0f;
#pragma unroll
        for (int j = 0; j < 4; ++j) {
            f32x4 v = px[lane + j * 64];
            s += (v.x + v.y) + (v.z + v.w);
        }
#pragma unroll
        for (int off = 32; off > 0; off >>= 1)
            s += __shfl_down(s, off, 64);
        if (lane == 0)
            mean[p] = s * (1.0f / (float)HW);
    }
}

// ---------------- Kernel 2: FC1 -> relu -> FC2 -> sigmoid/bias ----------------
// One block (256 threads) per batch element in the chunk.
__global__ void se_fc_kernel(const float* __restrict__ mean,
                             const float* __restrict__ fc1_w,  // [SE_CH][CH]
                             const float* __restrict__ fc1_b,  // [SE_CH]
                             const float* __restrict__ fc2_w,  // [2*CH][SE_CH]
                             const float* __restrict__ fc2_b,  // [2*CH]
                             float* __restrict__ scale,        // [chunk][CH]
                             float* __restrict__ bias) {       // [chunk][CH]
    const int b = blockIdx.x;
    const int t = threadIdx.x;
    __shared__ float m[CH];
    __shared__ float se[SE_CH];

    for (int i = t; i < CH; i += blockDim.x)
        m[i] = mean[b * CH + i];
    __syncthreads();

    // FC1: 32 outputs x 8 threads each; each thread sums 64 elems, reduce in 8-lane groups.
    {
        const int o = t >> 3;   // 0..31
        const int p = t & 7;
        float acc = 0.0f;
        const float* wr = fc1_w + o * CH + p * 64;
        const float* mr = m + p * 64;
#pragma unroll 16
        for (int k = 0; k < 64; ++k)
            acc = fmaf(wr[k], mr[k], acc);
#pragma unroll
        for (int off = 4; off > 0; off >>= 1)
            acc += __shfl_xor(acc, off, 8);
        if (p == 0)
            se[o] = fmaxf(acc + fc1_b[o], 0.0f);
    }
    __syncthreads();

    // FC2: 2*CH = 1024 outputs, 256 threads -> 4 per thread
    for (int o = t; o < 2 * CH; o += blockDim.x) {
        float acc = fc2_b[o];
        const float* wr = fc2_w + o * SE_CH;
#pragma unroll
        for (int k = 0; k < SE_CH; ++k)
            acc = fmaf(wr[k], se[k], acc);
        if (o < CH)
            scale[b * CH + o] = 1.0f / (1.0f + expf(-acc));
        else
            bias[b * CH + (o - CH)] = acc;
    }
}

// ---------------- Kernel 3: out = x * scale[plane] + bias[plane] ----------------
// x-reads should hit L3 (chunk was just streamed by the mean kernel);
// out-writes are nontemporal so they don't evict the x chunk.
__global__ void se_apply_kernel(const float* __restrict__ x,
                                const float* __restrict__ scale,
                                const float* __restrict__ bias,
                                float* __restrict__ out,
                                size_t n4) {
    size_t i = blockIdx.x * (size_t)blockDim.x + threadIdx.x;
    const size_t stride = (size_t)gridDim.x * blockDim.x;
    const f32x4* x4 = (const f32x4*)x;
    f32x4* o4 = (f32x4*)out;

    for (; i < n4; i += stride) {
        const int plane = (int)(i >> 8);  // 256 f32x4 per 1024-elem plane
        const float s = scale[plane];
        const float bi = bias[plane];
        f32x4 v = x4[i];
        f32x4 r;
        r.x = fmaf(v.x, s, bi);
        r.y = fmaf(v.y, s, bi);
        r.z = fmaf(v.z, s, bi);
        r.w = fmaf(v.w, s, bi);
        __builtin_nontemporal_store(r, &o4[i]);
    }
}

extern "C" void kernel_launch(void* const* d_in, const int* in_sizes, int n_in,
                              void* d_out, int out_size, void* d_ws, size_t ws_size,
                              hipStream_t stream) {
    const float* x     = (const float*)d_in[0];
    const float* fc1_w = (const float*)d_in[1];
    const float* fc1_b = (const float*)d_in[2];
    const float* fc2_w = (const float*)d_in[3];
    const float* fc2_b = (const float*)d_in[4];
    float* out = (float*)d_out;

    const int nplanes = BATCH * CH;            // 131072
    float* mean  = (float*)d_ws;               // 131072 f32
    float* scale = mean + nplanes;             // 131072 f32
    float* bias  = scale + nplanes;            // 131072 f32

    for (int ck = 0; ck < NCHUNK; ++ck) {
        const size_t po = (size_t)ck * CHUNK_PLANES;   // plane offset
        const float* xc = x + po * HW;
        float* oc = out + po * HW;

        // 1) chunk means: 1024 blocks * 4 waves = 4096 waves, 8 planes/wave
        se_mean_kernel<<<1024, 256, 0, stream>>>(xc, mean + po, CHUNK_PLANES);

        // 2) FC stack for the chunk's batches
        se_fc_kernel<<<CHUNK_B, 256, 0, stream>>>(mean + po, fc1_w, fc1_b,
                                                  fc2_w, fc2_b,
                                                  scale + po, bias + po);

        // 3) streaming apply over the chunk
        se_apply_kernel<<<2048, 256, 0, stream>>>(xc, scale + po, bias + po, oc,
                                                  (size_t)CHUNK_PLANES * (HW / 4));
    }
}

// Round 3
// 279.692 us; speedup vs baseline: 1.2941x; 1.0853x over previous
//
#include <hip/hip_runtime.h>
#include <math.h>

#define BATCH 256
#define CH 512
#define SE_CH 32
#define HW 1024                       // 32*32
#define CHUNK_B 64                    // 64 batches = 128 MB of x per chunk
#define NCHUNK (BATCH / CHUNK_B)      // 4
#define CHUNK_PLANES (CHUNK_B * CH)   // 32768
#define SUBS 8                        // apply blocks per batch element
#define CPS (CH / SUBS)               // channels per apply block = 64
#define NA_BLOCKS (CHUNK_B * SUBS)    // 512 apply blocks per chunk
#define NM_BLOCKS 512                 // mean-role blocks in fused kernels

typedef float f32x4 __attribute__((ext_vector_type(4)));

// Fused kernel, role split by blockIdx:
//   blockIdx < na           : apply chunk at apply_b0 (FC recomputed per block from mean_ws)
//   blockIdx in [na, grid)  : plane means for planes [mean_p0, mean_p0+mean_np)
__global__ __launch_bounds__(256) void se_fused(
        const float* __restrict__ x,
        float* __restrict__ out,
        float* __restrict__ mean_ws,          // [BATCH*CH]
        const float* __restrict__ fc1_w,      // [SE_CH][CH]
        const float* __restrict__ fc1_b,      // [SE_CH]
        const float* __restrict__ fc2_w,      // [2*CH][SE_CH]
        const float* __restrict__ fc2_b,      // [2*CH]
        int na, int apply_b0, int mean_p0, int mean_np) {
    const int t = threadIdx.x;
    __shared__ float m[CH];
    __shared__ float se[SE_CH];
    __shared__ float sc[CPS];
    __shared__ float bi[CPS];

    if ((int)blockIdx.x < na) {
        // ---------------- apply role ----------------
        const int ab = blockIdx.x;
        const int b = apply_b0 + (ab >> 3);   // batch element
        const int sub = ab & 7;               // 64-channel slice

        for (int i = t; i < CH; i += 256)
            m[i] = mean_ws[(size_t)b * CH + i];
        __syncthreads();

        // FC1: output o = t>>3, partial p = t&7 over k = p+8j (LDS conflict-free)
        {
            const int o = t >> 3;
            const int p = t & 7;
            const float* wr = fc1_w + o * CH;
            float acc = 0.0f;
#pragma unroll
            for (int j = 0; j < 64; ++j) {
                const int k = p + 8 * j;
                acc = fmaf(wr[k], m[k], acc);
            }
            acc += __shfl_xor(acc, 4, 8);
            acc += __shfl_xor(acc, 2, 8);
            acc += __shfl_xor(acc, 1, 8);
            if (p == 0)
                se[o] = fmaxf(acc + fc1_b[o], 0.0f);
        }
        __syncthreads();

        // FC2 for this block's 64 channels: t<64 -> scale, 64<=t<128 -> bias
        if (t < 2 * CPS) {
            const int c = sub * CPS + (t & (CPS - 1));
            const int o = (t < CPS) ? c : (CH + c);
            float acc = fc2_b[o];
            const float* wr = fc2_w + o * SE_CH;
#pragma unroll
            for (int k = 0; k < SE_CH; ++k)
                acc = fmaf(wr[k], se[k], acc);
            if (t < CPS)
                sc[t] = 1.0f / (1.0f + expf(-acc));
            else
                bi[t - CPS] = acc;
        }
        __syncthreads();

        // apply 64 planes; thread t does f32x4 #t of each plane
        const size_t base = ((size_t)b * CH + (size_t)sub * CPS) * HW;
        const f32x4* xp = (const f32x4*)(x + base);
        f32x4* op = (f32x4*)(out + base);
#pragma unroll 4
        for (int p = 0; p < CPS; ++p) {
            const float s = sc[p];
            const float bb = bi[p];
            f32x4 v = xp[p * 256 + t];
            f32x4 r;
            r.x = fmaf(v.x, s, bb);
            r.y = fmaf(v.y, s, bb);
            r.z = fmaf(v.z, s, bb);
            r.w = fmaf(v.w, s, bb);
            __builtin_nontemporal_store(r, &op[p * 256 + t]);
        }
    } else {
        // ---------------- mean role ----------------
        const int lane = t & 63;
        const int wib = t >> 6;
        int wid = ((int)blockIdx.x - na) * 4 + wib;
        const int nw = ((int)gridDim.x - na) * 4;
        for (int p = wid; p < mean_np; p += nw) {
            const f32x4* px = (const f32x4*)(x + (size_t)(mean_p0 + p) * HW);
            float s = 0.0f;
#pragma unroll
            for (int j = 0; j < 4; ++j) {
                f32x4 v = px[lane + j * 64];
                s += (v.x + v.y) + (v.z + v.w);
            }
#pragma unroll
            for (int off = 32; off > 0; off >>= 1)
                s += __shfl_down(s, off, 64);
            if (lane == 0)
                mean_ws[mean_p0 + p] = s * (1.0f / (float)HW);
        }
    }
}

extern "C" void kernel_launch(void* const* d_in, const int* in_sizes, int n_in,
                              void* d_out, int out_size, void* d_ws, size_t ws_size,
                              hipStream_t stream) {
    const float* x     = (const float*)d_in[0];
    const float* fc1_w = (const float*)d_in[1];
    const float* fc1_b = (const float*)d_in[2];
    const float* fc2_w = (const float*)d_in[3];
    const float* fc2_b = (const float*)d_in[4];
    float* out = (float*)d_out;
    float* mean = (float*)d_ws;   // BATCH*CH f32

    // Prologue: means of chunk 0 (all-mean config)
    se_fused<<<2048, 256, 0, stream>>>(x, out, mean, fc1_w, fc1_b, fc2_w, fc2_b,
                                       0, 0, 0, CHUNK_PLANES);

    // Steady state: apply(k) + mean(k+1) fused
    for (int k = 0; k < NCHUNK - 1; ++k) {
        se_fused<<<NA_BLOCKS + NM_BLOCKS, 256, 0, stream>>>(
            x, out, mean, fc1_w, fc1_b, fc2_w, fc2_b,
            NA_BLOCKS, k * CHUNK_B, (k + 1) * CHUNK_PLANES, CHUNK_PLANES);
    }

    // Epilogue: apply last chunk (no mean role)
    se_fused<<<NA_BLOCKS, 256, 0, stream>>>(
        x, out, mean, fc1_w, fc1_b, fc2_w, fc2_b,
        NA_BLOCKS, (NCHUNK - 1) * CHUNK_B, 0, 0);
}